// Round 1
// baseline (299.456 us; speedup 1.0000x reference)
//
#include <hip/hip_runtime.h>

typedef float v4 __attribute__((ext_vector_type(4)));
typedef float v2 __attribute__((ext_vector_type(2)));

__device__ __forceinline__ float leaky(float x) { return x >= 0.f ? x : 0.2f * x; }
__device__ __forceinline__ float elu(float x) { return x > 0.f ? x : expm1f(x); }

// ---------------- CSR build (dst-major) ----------------
__global__ void k_deg(const int* __restrict__ ei, int* __restrict__ deg, int nE, int eT) {
  int e = blockIdx.x * blockDim.x + threadIdx.x;
  if (e >= eT) return;
  int d = (e < nE) ? ei[nE + e] : (e - nE);   // self-loops appended after real edges
  atomicAdd(&deg[d], 1);
}

__global__ void k_scan(const int* __restrict__ deg, int* __restrict__ rowptr,
                       int* __restrict__ cursor, int nN, int eT) {
  __shared__ int sd[1024];
  int t = threadIdx.x;
  int chunk = (nN + 1023) >> 10;
  int beg = t * chunk;
  int end = beg + chunk; if (end > nN) end = nN;
  int s = 0;
  for (int i = beg; i < end; ++i) s += deg[i];
  sd[t] = s;
  __syncthreads();
  for (int off = 1; off < 1024; off <<= 1) {
    int v = (t >= off) ? sd[t - off] : 0;
    __syncthreads();
    sd[t] += v;
    __syncthreads();
  }
  int run = sd[t] - s;  // exclusive prefix of this thread's chunk
  for (int i = beg; i < end; ++i) { rowptr[i] = run; cursor[i] = run; run += deg[i]; }
  if (t == 0) rowptr[nN] = eT;
}

__global__ void k_scatter(const int* __restrict__ ei, int* __restrict__ cursor,
                          int* __restrict__ srt, int nE, int eT) {
  int e = blockIdx.x * blockDim.x + threadIdx.x;
  if (e >= eT) return;
  int s, d;
  if (e < nE) { s = ei[e]; d = ei[nE + e]; } else { s = d = e - nE; }
  int pos = atomicAdd(&cursor[d], 1);
  srt[pos] = s;
}

// ---- prep: uv[k][0..3] = W1[k,h*64:+64]·att_src1_h ; uv[k][4..7] = same with att_dst1 ----
__global__ __launch_bounds__(256) void k_prep(const float* __restrict__ W1,
                                              const float* __restrict__ asv,
                                              const float* __restrict__ adv,
                                              float* __restrict__ uv) {
  int i = blockIdx.x * 256 + threadIdx.x;   // 0..511
  if (i >= 512) return;
  int k = i >> 2, h = i & 3;
  const float* w = &W1[(size_t)k * 256 + h * 64];
  const float* a = &asv[h * 64];
  const float* d = &adv[h * 64];
  float su = 0.f, sv = 0.f;
  #pragma unroll 8
  for (int c = 0; c < 64; ++c) { float x = w[c]; su += x * a[c]; sv += x * d[c]; }
  uv[k * 8 + h]     = su;
  uv[k * 8 + 4 + h] = sv;
}

// ---- attn1: as1[n,h] = x[n]·u_h, ad1[n,h] = x[n]·v_h  (wave per node) ----
__global__ __launch_bounds__(256) void k_attn1(
    const int* __restrict__ nidx, const float* __restrict__ emb,
    const float* __restrict__ uv, float* __restrict__ as1,
    float* __restrict__ ad1, int nN) {
  int t = threadIdx.x;
  int wv = t >> 6, lane = t & 63;
  int n = blockIdx.x * 4 + wv;
  if (n >= nN) return;
  const float* xp = &emb[(size_t)nidx[n] * 128];
  v2 x = *(const v2*)&xp[lane * 2];
  v4 u0 = *(const v4*)&uv[(lane * 2) * 8];
  v4 d0 = *(const v4*)&uv[(lane * 2) * 8 + 4];
  v4 u1 = *(const v4*)&uv[(lane * 2 + 1) * 8];
  v4 d1 = *(const v4*)&uv[(lane * 2 + 1) * 8 + 4];
  v4 ps = u0 * x[0] + u1 * x[1];
  v4 pd = d0 * x[0] + d1 * x[1];
  for (int o = 32; o; o >>= 1) {
    ps[0] += __shfl_xor(ps[0], o); ps[1] += __shfl_xor(ps[1], o);
    ps[2] += __shfl_xor(ps[2], o); ps[3] += __shfl_xor(ps[3], o);
    pd[0] += __shfl_xor(pd[0], o); pd[1] += __shfl_xor(pd[1], o);
    pd[2] += __shfl_xor(pd[2], o); pd[3] += __shfl_xor(pd[3], o);
  }
  if (lane == 0) {
    *(v4*)&as1[(size_t)n * 4] = ps;
    *(v4*)&ad1[(size_t)n * 4] = pd;
  }
}

// ---- layer-1 aggregation in INPUT space: g[n,h,:] = (Σ_s w_h emb[nidx[s],:]) / Σ_s w_h ----
// One wave per node, barrier-free (wave-private LDS scratch). Gathers 512B/edge (was 1KB).
__global__ __launch_bounds__(256) void k_aggx(
    const int* __restrict__ nidx, const float* __restrict__ emb,
    const float* __restrict__ as1, const float* __restrict__ ad1,
    const int* __restrict__ rowptr, const int* __restrict__ srt,
    float* __restrict__ g, int nN) {
  __shared__ int   ss[4][64];
  __shared__ float sw[4][256];
  int t = threadIdx.x;
  int wv = t >> 6, lane = t & 63;
  int n = blockIdx.x * 4 + wv;
  if (n >= nN) return;                     // whole wave exits; no barriers in kernel
  int ms0 = rowptr[n], ms1 = rowptr[n + 1];
  v4 adn = *(const v4*)&ad1[(size_t)n * 4];
  v2 acc0 = (v2)(0.f), acc1 = (v2)(0.f), acc2 = (v2)(0.f), acc3 = (v2)(0.f);
  float den0 = 0.f, den1 = 0.f, den2 = 0.f, den3 = 0.f;
  for (int base = ms0; base < ms1; base += 64) {
    int m = ms1 - base; if (m > 64) m = 64;
    asm volatile("s_waitcnt lgkmcnt(0)" ::: "memory");
    __builtin_amdgcn_wave_barrier();
    if (lane < m) {
      int s = srt[base + lane];
      ss[wv][lane] = nidx[s];              // resolve emb row at staging time
      v4 a = *(const v4*)&as1[(size_t)s * 4];
      sw[wv][lane * 4 + 0] = __expf(leaky(a[0] + adn[0]));
      sw[wv][lane * 4 + 1] = __expf(leaky(a[1] + adn[1]));
      sw[wv][lane * 4 + 2] = __expf(leaky(a[2] + adn[2]));
      sw[wv][lane * 4 + 3] = __expf(leaky(a[3] + adn[3]));
    }
    asm volatile("s_waitcnt lgkmcnt(0)" ::: "memory");
    __builtin_amdgcn_wave_barrier();
    #pragma unroll 8
    for (int j = 0; j < m; ++j) {
      int r = ss[wv][j];
      v4 w = *(const v4*)&sw[wv][j * 4];
      v2 xv = *(const v2*)&emb[(size_t)r * 128 + lane * 2];
      acc0 += w[0] * xv; den0 += w[0];
      acc1 += w[1] * xv; den1 += w[1];
      acc2 += w[2] * xv; den2 += w[2];
      acc3 += w[3] * xv; den3 += w[3];
    }
  }
  size_t gb = (size_t)n * 512 + lane * 2;
  *(v2*)&g[gb + 0]   = acc0 * (1.f / den0);
  *(v2*)&g[gb + 128] = acc1 * (1.f / den1);
  *(v2*)&g[gb + 256] = acc2 * (1.f / den2);
  *(v2*)&g[gb + 384] = acc3 * (1.f / den3);
}

// ---- GEMM1b: x2[n, h*64+c] = elu( g[n,h,:]·W1[:,h*64+c] + b1 )  (per-head 128x64 GEMM) ----
// grid: (node-tiles of 64) x (4 heads); block 256 thr; thread tile 4n x 4c.
__global__ __launch_bounds__(256) void k_gemm1b(
    const float* __restrict__ g, const float* __restrict__ W1,
    const float* __restrict__ b1, float* __restrict__ x2, int nN) {
  __shared__ __align__(16) float xs[64 * 68];  // [n][k], stride 68
  __shared__ __align__(16) float Ws[64 * 64];  // [k][c] row-major
  int t = threadIdx.x;
  int nbase = (blockIdx.x >> 2) * 64;
  int head  = blockIdx.x & 3;
  int cbase = head * 64;
  int c0 = (t & 15) * 4;
  int n0 = (t >> 4) * 4;
  float acc[4][4];
  for (int i = 0; i < 4; ++i) for (int j = 0; j < 4; ++j) acc[i][j] = 0.f;
  v4 z = (v4)(0.f);
  for (int kc = 0; kc < 2; ++kc) {
    __syncthreads();
    {  // stage g: thread -> node t>>2, 16 k-floats
      int sn = t >> 2;
      int node = nbase + sn;
      int kp = (t & 3) * 16;
      bool v = node < nN;
      const float* sp = &g[(size_t)(v ? node : nN - 1) * 512 + head * 128 + kc * 64 + kp];
      v4 a0 = v ? *(const v4*)(sp + 0)  : z;
      v4 a1 = v ? *(const v4*)(sp + 4)  : z;
      v4 a2 = v ? *(const v4*)(sp + 8)  : z;
      v4 a3 = v ? *(const v4*)(sp + 12) : z;
      *(v4*)&xs[sn * 68 + kp + 0]  = a0;
      *(v4*)&xs[sn * 68 + kp + 4]  = a1;
      *(v4*)&xs[sn * 68 + kp + 8]  = a2;
      *(v4*)&xs[sn * 68 + kp + 12] = a3;
    }
    {  // stage W: thread -> k-row t>>2, 16 c-floats
      int kk = t >> 2;
      int cp = (t & 3) * 16;
      const float* wp = &W1[(size_t)(kc * 64 + kk) * 256 + cbase + cp];
      v4 w0 = *(const v4*)(wp + 0);
      v4 w1 = *(const v4*)(wp + 4);
      v4 w2 = *(const v4*)(wp + 8);
      v4 w3 = *(const v4*)(wp + 12);
      *(v4*)&Ws[kk * 64 + cp + 0]  = w0;
      *(v4*)&Ws[kk * 64 + cp + 4]  = w1;
      *(v4*)&Ws[kk * 64 + cp + 8]  = w2;
      *(v4*)&Ws[kk * 64 + cp + 12] = w3;
    }
    __syncthreads();
    #pragma unroll 4
    for (int kk = 0; kk < 64; kk += 4) {
      v4 xv[4], wv[4];
      for (int i = 0; i < 4; ++i) xv[i] = *(const v4*)&xs[(n0 + i) * 68 + kk];
      for (int j = 0; j < 4; ++j) wv[j] = *(const v4*)&Ws[(kk + j) * 64 + c0];
      for (int i = 0; i < 4; ++i)
        for (int j = 0; j < 4; ++j) {
          float xd = xv[i][j];
          acc[i][0] += xd * wv[j][0];
          acc[i][1] += xd * wv[j][1];
          acc[i][2] += xd * wv[j][2];
          acc[i][3] += xd * wv[j][3];
        }
    }
  }
  v4 bb = *(const v4*)&b1[cbase + c0];
  for (int i = 0; i < 4; ++i) {
    int node = nbase + n0 + i;
    if (node < nN) {
      v4 o;
      o[0] = elu(acc[i][0] + bb[0]);
      o[1] = elu(acc[i][1] + bb[1]);
      o[2] = elu(acc[i][2] + bb[2]);
      o[3] = elu(acc[i][3] + bb[3]);
      *(v4*)&x2[(size_t)node * 256 + cbase + c0] = o;
    }
  }
}

// ---- GEMM2: h2[n,64] = x2[n,256] @ W2[256,64]; epilogue computes as2/ad2 ----
__global__ __launch_bounds__(256) void k_gemm2(
    const float* __restrict__ x2, const float* __restrict__ W2,
    const float* __restrict__ asv, const float* __restrict__ adv,
    float* __restrict__ h2, float* __restrict__ as2, float* __restrict__ ad2, int nN) {
  __shared__ __align__(16) float xs[32 * 68];  // [n][k], stride 68
  __shared__ __align__(16) float Ws[64 * 64];  // [k][c] row-major
  int t = threadIdx.x;
  int nbase = blockIdx.x * 32;
  int c0 = (t & 15) * 4;
  int n0 = (t >> 4) * 2;
  float acc[2][4];
  for (int i = 0; i < 2; ++i) for (int j = 0; j < 4; ++j) acc[i][j] = 0.f;
  v4 z = (v4)(0.f);
  for (int kc = 0; kc < 4; ++kc) {
    __syncthreads();
    {  // stage x: thread -> node t>>3, 8 k-floats
      int sn = t >> 3;
      int node = nbase + sn;
      int kp = (t & 7) * 8;
      bool v = node < nN;
      const float* sp = &x2[(size_t)(v ? node : nN - 1) * 256 + kc * 64 + kp];
      v4 a0 = v ? *(const v4*)(sp + 0) : z;
      v4 a1 = v ? *(const v4*)(sp + 4) : z;
      *(v4*)&xs[sn * 68 + kp + 0] = a0;
      *(v4*)&xs[sn * 68 + kp + 4] = a1;
    }
    {  // stage W: thread -> k-row t>>2, 16 c-floats
      int kk = t >> 2;
      int cp = (t & 3) * 16;
      const float* wp = &W2[(size_t)(kc * 64 + kk) * 64 + cp];
      v4 w0 = *(const v4*)(wp + 0);
      v4 w1 = *(const v4*)(wp + 4);
      v4 w2 = *(const v4*)(wp + 8);
      v4 w3 = *(const v4*)(wp + 12);
      *(v4*)&Ws[kk * 64 + cp + 0]  = w0;
      *(v4*)&Ws[kk * 64 + cp + 4]  = w1;
      *(v4*)&Ws[kk * 64 + cp + 8]  = w2;
      *(v4*)&Ws[kk * 64 + cp + 12] = w3;
    }
    __syncthreads();
    #pragma unroll 4
    for (int kk = 0; kk < 64; kk += 4) {
      v4 xv[2], wv[4];
      for (int i = 0; i < 2; ++i) xv[i] = *(const v4*)&xs[(n0 + i) * 68 + kk];
      for (int j = 0; j < 4; ++j) wv[j] = *(const v4*)&Ws[(kk + j) * 64 + c0];
      for (int i = 0; i < 2; ++i)
        for (int j = 0; j < 4; ++j) {
          float xd = xv[i][j];
          acc[i][0] += xd * wv[j][0];
          acc[i][1] += xd * wv[j][1];
          acc[i][2] += xd * wv[j][2];
          acc[i][3] += xd * wv[j][3];
        }
    }
  }
  v4 asl = *(const v4*)&asv[c0];
  v4 adl = *(const v4*)&adv[c0];
  for (int i = 0; i < 2; ++i) {
    int node = nbase + n0 + i;
    v4 o; o[0] = acc[i][0]; o[1] = acc[i][1]; o[2] = acc[i][2]; o[3] = acc[i][3];
    float ps = o[0]*asl[0] + o[1]*asl[1] + o[2]*asl[2] + o[3]*asl[3];
    float pd = o[0]*adl[0] + o[1]*adl[1] + o[2]*adl[2] + o[3]*adl[3];
    ps += __shfl_xor(ps, 1); pd += __shfl_xor(pd, 1);
    ps += __shfl_xor(ps, 2); pd += __shfl_xor(pd, 2);
    ps += __shfl_xor(ps, 4); pd += __shfl_xor(pd, 4);
    ps += __shfl_xor(ps, 8); pd += __shfl_xor(pd, 8);
    if (node < nN) {
      *(v4*)&h2[(size_t)node * 64 + c0] = o;
      if ((t & 15) == 0) { as2[node] = ps; ad2[node] = pd; }
    }
  }
}

// ---- layer-2 softmax + aggregate + bias + ELU: one wave per node, barrier-free ----
// Vectorized: 4 edges per wave-step, v4 loads (16B/lane), cross-group shfl reduce.
__global__ __launch_bounds__(256) void k_agg2(
    const float* __restrict__ h2, const float* __restrict__ as2,
    const float* __restrict__ ad2, const float* __restrict__ b2,
    const int* __restrict__ rowptr, const int* __restrict__ srt,
    float* __restrict__ x3, int nN) {
  __shared__ int   ss[4][64];
  __shared__ float sw[4][64];
  int t = threadIdx.x;
  int wv = t >> 6, lane = t & 63;
  int n = blockIdx.x * 4 + wv;
  if (n >= nN) return;                     // whole wave exits; no barriers in kernel
  int ms0 = rowptr[n], ms1 = rowptr[n + 1];
  float adn = ad2[n];
  int grp = lane >> 4;        // which edge of the quad
  int c4  = (lane & 15) * 4;  // dim group
  v4 acc = (v4)(0.f);
  float den = 0.f;
  for (int base = ms0; base < ms1; base += 64) {
    int m = ms1 - base; if (m > 64) m = 64;
    asm volatile("s_waitcnt lgkmcnt(0)" ::: "memory");
    __builtin_amdgcn_wave_barrier();
    {
      int s = 0; float ww = 0.f;
      if (lane < m) { s = srt[base + lane]; ww = __expf(leaky(as2[s] + adn)); }
      ss[wv][lane] = s;        // pad with row 0, weight 0
      sw[wv][lane] = ww;
    }
    asm volatile("s_waitcnt lgkmcnt(0)" ::: "memory");
    __builtin_amdgcn_wave_barrier();
    int mq = (m + 3) & ~3;
    #pragma unroll 4
    for (int j = 0; j < mq; j += 4) {
      int s = ss[wv][j + grp];
      float wj = sw[wv][j + grp];
      v4 hv = *(const v4*)&h2[(size_t)s * 64 + c4];
      acc += wj * hv;
      den += wj;
    }
  }
  // reduce across the 4 edge-groups (lane bits 4 and 5)
  acc[0] += __shfl_xor(acc[0], 16); acc[1] += __shfl_xor(acc[1], 16);
  acc[2] += __shfl_xor(acc[2], 16); acc[3] += __shfl_xor(acc[3], 16);
  den += __shfl_xor(den, 16);
  acc[0] += __shfl_xor(acc[0], 32); acc[1] += __shfl_xor(acc[1], 32);
  acc[2] += __shfl_xor(acc[2], 32); acc[3] += __shfl_xor(acc[3], 32);
  den += __shfl_xor(den, 32);
  if (lane < 16) {
    float inv = 1.f / den;
    v4 bb = *(const v4*)&b2[c4];
    v4 o;
    o[0] = elu(acc[0] * inv + bb[0]);
    o[1] = elu(acc[1] * inv + bb[1]);
    o[2] = elu(acc[2] * inv + bb[2]);
    o[3] = elu(acc[3] * inv + bb[3]);
    *(v4*)&x3[(size_t)n * 64 + c4] = o;
  }
}

// ---- fused gate MLP + pooling partials (exactly 256 blocks x 512 threads) ----
__global__ __launch_bounds__(512) void k_gatepool(
    const float* __restrict__ x3, const float* __restrict__ gW1,
    const float* __restrict__ gb1, const float* __restrict__ gW2,
    const float* __restrict__ gb2, float* __restrict__ pnum,
    float* __restrict__ pden, int nN) {
  __shared__ __align__(16) float gwT[64 * 68];   // gW1^T, padded (4-float aligned)
  __shared__ float xr[8][64];
  __shared__ float snum[8][64];
  __shared__ float sden[8];
  int t = threadIdx.x;
  int wv = t >> 6, lane = t & 63;
  for (int i = t; i < 4096; i += 512) {
    int d = i >> 6, c = i & 63;
    gwT[c * 68 + d] = gW1[i];
  }
  float gb1l = gb1[lane];
  float gw2l = gW2[lane];
  float gb2s = gb2[0];
  __syncthreads();
  float num = 0.f, den = 0.f;
  int nIt = (nN + 2047) >> 11;
  int off0 = blockIdx.x * 8 + wv;
  for (int it = 0; it < nIt; ++it) {
    int n = off0 + it * 2048;
    bool v = n < nN;
    float xv = v ? x3[(size_t)n * 64 + lane] : 0.f;
    xr[wv][lane] = xv;
    asm volatile("s_waitcnt lgkmcnt(0)" ::: "memory");
    __builtin_amdgcn_wave_barrier();
    float hid = gb1l;
    for (int d4 = 0; d4 < 64; d4 += 4) {
      v4 xs4 = *(const v4*)&xr[wv][d4];
      v4 gv  = *(const v4*)&gwT[lane * 68 + d4];
      hid += xs4[0] * gv[0] + xs4[1] * gv[1] + xs4[2] * gv[2] + xs4[3] * gv[3];
    }
    hid = fmaxf(hid, 0.f);
    float p = hid * gw2l;
    for (int o = 32; o; o >>= 1) p += __shfl_xor(p, o);
    float g = __expf(p + gb2s);
    if (v) { num += g * xv; den += g; }
    asm volatile("s_waitcnt lgkmcnt(0)" ::: "memory");
    __builtin_amdgcn_wave_barrier();
  }
  snum[wv][lane] = num;
  if (lane == 0) sden[wv] = den;
  __syncthreads();
  if (t < 64) {
    float s = 0.f;
    for (int k = 0; k < 8; ++k) s += snum[k][t];
    pnum[blockIdx.x * 64 + t] = s;
  }
  if (t == 0) {
    float s = 0.f;
    for (int k = 0; k < 8; ++k) s += sden[k];
    pden[blockIdx.x] = s;
  }
}

__global__ void k_final(const float* __restrict__ pnum, const float* __restrict__ pden,
                        float* __restrict__ out) {
  int t = threadIdx.x;  // 64 threads
  float s = 0.f, dn = 0.f;
  for (int b = 0; b < 256; ++b) { s += pnum[b * 64 + t]; dn += pden[b]; }
  out[t] = s / dn;
}

extern "C" void kernel_launch(void* const* d_in, const int* in_sizes, int n_in,
                              void* d_out, int out_size, void* d_ws, size_t ws_size,
                              hipStream_t stream) {
  const int*   nidx = (const int*)d_in[0];
  const int*   ei   = (const int*)d_in[1];
  const float* emb  = (const float*)d_in[2];
  const float* W1   = (const float*)d_in[3];
  const float* as1v = (const float*)d_in[4];
  const float* ad1v = (const float*)d_in[5];
  const float* b1   = (const float*)d_in[6];
  const float* W2   = (const float*)d_in[7];
  const float* as2v = (const float*)d_in[8];
  const float* ad2v = (const float*)d_in[9];
  const float* b2   = (const float*)d_in[10];
  const float* gW1  = (const float*)d_in[11];
  const float* gb1  = (const float*)d_in[12];
  const float* gW2  = (const float*)d_in[13];
  const float* gb2  = (const float*)d_in[14];
  float* out = (float*)d_out;

  const int nN = in_sizes[0];
  const int nE = in_sizes[1] / 2;
  const int eT = nE + nN;

  float* f = (float*)d_ws;
  size_t off = 0;
  float* g    = f + off; off += (size_t)nN * 512;  // [N][4 heads][128] pre-divided agg
  float* x2   = f + off; off += (size_t)nN * 256;
  float* as1  = f + off; off += (size_t)nN * 4;
  float* ad1  = f + off; off += (size_t)nN * 4;
  float* as2  = f + off; off += nN;
  float* ad2  = f + off; off += nN;
  float* uv   = f + off; off += 1024;              // [128][8]: u_h (src) | v_h (dst)
  float* pnum = f + off; off += 256 * 64;
  float* pden = f + off; off += 256;
  int* deg    = (int*)(f + off); off += nN;
  int* rowptr = (int*)(f + off); off += nN + 1;
  int* cursor = (int*)(f + off); off += nN;
  int* srt    = (int*)(f + off); off += eT;

  float* h2 = g;                        // g dead after k_gemm1b
  float* x3 = g + (size_t)nN * 64;      // disjoint from h2 (nN*64)

  hipMemsetAsync(deg, 0, (size_t)nN * sizeof(int), stream);

  int eb = (eT + 255) / 256;
  k_deg    <<<eb, 256, 0, stream>>>(ei, deg, nE, eT);
  k_scan   <<<1, 1024, 0, stream>>>(deg, rowptr, cursor, nN, eT);
  k_scatter<<<eb, 256, 0, stream>>>(ei, cursor, srt, nE, eT);

  k_prep  <<<2, 256, 0, stream>>>(W1, as1v, ad1v, uv);
  k_attn1 <<<(nN + 3) / 4, 256, 0, stream>>>(nidx, emb, uv, as1, ad1, nN);
  k_aggx  <<<(nN + 3) / 4, 256, 0, stream>>>(nidx, emb, as1, ad1, rowptr, srt, g, nN);

  int nt64 = (nN + 63) / 64;
  k_gemm1b<<<nt64 * 4, 256, 0, stream>>>(g, W1, b1, x2, nN);

  k_gemm2 <<<(nN + 31) / 32, 256, 0, stream>>>(x2, W2, as2v, ad2v, h2, as2, ad2, nN);
  k_agg2  <<<(nN + 3) / 4, 256, 0, stream>>>(h2, as2, ad2, b2, rowptr, srt, x3, nN);

  k_gatepool<<<256, 512, 0, stream>>>(x3, gW1, gb1, gW2, gb2, pnum, pden, nN);
  k_final   <<<1, 64, 0, stream>>>(pnum, pden, out);
}